// Round 20
// baseline (565.137 us; speedup 1.0000x reference)
//
#include <hip/hip_runtime.h>
#include <stdint.h>

// ---- problem constants ----
#define B_  2
#define N_  2048
#define C_  768
#define H_  12
#define NT  (B_*N_)      // 4096 tokens
#define C3  (3*C_)       // 2304

typedef _Float16 h8 __attribute__((ext_vector_type(8)));   // 4 VGPR, fp16x8 MFMA frag
typedef _Float16 h4 __attribute__((ext_vector_type(4)));
typedef float    f4 __attribute__((ext_vector_type(4)));   // fp32x4 accumulator
typedef float    f16x __attribute__((ext_vector_type(16)));// 32x32 accumulator
typedef uint32_t u4 __attribute__((ext_vector_type(4)));

__device__ __forceinline__ void gload16(const void* g, void* l) {
  // async global->LDS, 16B per lane; LDS dest = wave-uniform base + lane*16
  __builtin_amdgcn_global_load_lds((const __attribute__((address_space(1))) void*)g,
                                   (__attribute__((address_space(3))) void*)l,
                                   16, 0, 0);
}

// T1: XCD-aware bijective block swizzle (m157).  Requires nwg%8==0.
__device__ __forceinline__ int xcd_swz(int flat, int nwg) {
  return (flat & 7) * (nwg >> 3) + (flat >> 3);
}

// ---------------- K1: fp32 -> fp16 convert (x, qkv_w, proj_w) ----------------
__global__ __launch_bounds__(256) void cvt3(const float* __restrict__ x,
                                            const float* __restrict__ w1,
                                            const float* __restrict__ w2,
                                            _Float16* __restrict__ xo,
                                            _Float16* __restrict__ w1o,
                                            _Float16* __restrict__ w2o) {
  const int NX8  = NT*C_/8;     // 393216
  const int NW18 = C3*C_/8;     // 221184
  int c = blockIdx.x*256 + threadIdx.x;
  const float* s; _Float16* d; int off;
  if (c < NX8)            { s = x;  d = xo;  off = c; }
  else if (c < NX8+NW18)  { s = w1; d = w1o; off = c - NX8; }
  else                    { s = w2; d = w2o; off = c - NX8 - NW18; }
  f4 a = *(const f4*)(s + (size_t)off*8);
  f4 b = *(const f4*)(s + (size_t)off*8 + 4);
  h8 o;
#pragma unroll
  for (int j = 0; j < 4; ++j) { o[j] = (_Float16)a[j]; o[j+4] = (_Float16)b[j]; }
  *(h8*)(d + (size_t)off*8) = o;
}

// ---------------- K2: fused QKV GEMM + bias + RoPE2D + scatter ----------------
// v4 (R19, final): 2D XCD chunking (FETCH 31.6->15.6MB), BK=64, XOR-swizzled
// LDS (conflicts 0), dbuf, 1 barrier/iter.  Structurally at its floor.
__global__ __launch_bounds__(256) void gemm_qkv(const _Float16* __restrict__ A,
                                                const _Float16* __restrict__ W,
                                                const float* __restrict__ bias,
                                                const int* __restrict__ pos2d,
                                                const void* __restrict__ maskraw,
                                                _Float16* __restrict__ Qd,
                                                _Float16* __restrict__ Kd,
                                                _Float16* __restrict__ Vtd) {
  constexpr int BM = 64, BN = 128, K = C_;
  __shared__ _Float16 Alds[2][BM*64];   // [row][col^] swizzled, 16 KB
  __shared__ _Float16 Wlds[2][BN*64];   // 32 KB
  __shared__ int sflags;
  const int tid = threadIdx.x, lane = tid & 63, w = tid >> 6;

  // --- sniff rope_mask dtype: 0=int32, 1=uint8/bool, 2=float32 ---
  if (tid == 0) sflags = 0;
  __syncthreads();
  const unsigned char* mbytes = (const unsigned char*)maskraw;
  int fl = 0;
#pragma unroll
  for (int k2 = 0; k2 < 16; ++k2) {
    unsigned char v = mbytes[tid*16 + k2];
    if (v == 0x3f) fl |= 1;
    if ((k2 & 3) && v) fl |= 2;
  }
  if (fl) atomicOr(&sflags, fl);   // visible after any later barrier

  // 2D XCD chunk: wid in [grp*144,(grp+1)*144) -> by = (grp&3)*16 + r/9,
  // bx = (grp>>2)*9 + r%9  (bijective; 3.34MB rectangle per XCD < 4MB L2)
  const int flat = blockIdx.y * gridDim.x + blockIdx.x;
  const int wid  = xcd_swz(flat, 18*64);
  const int grp = wid / 144, rr = wid % 144;
  const int by = (grp & 3)*16 + rr/9;
  const int bx = (grp >> 2)*9 + (rr % 9);
  const int m0 = by*BM, n0 = bx*BN;
  const int wm = w >> 1, wn = w & 1;
  const int fr = lane & 15, fq = lane >> 4;

  f4 acc[2][4] = {};

  // staging: linear LDS dest, pre-swizzled global source col (m173 pattern).
  const int srow = tid >> 3;                      // row-within-32
  const int scol = ((tid & 7) ^ (srow & 7)) * 8;  // swizzled source col (halfs)
  const _Float16* Agp0 = A + (size_t)(m0 +      srow)*K + scol;
  const _Float16* Agp1 = A + (size_t)(m0 + 32 + srow)*K + scol;
  const _Float16* Wgp0 = W + (size_t)(n0 +      srow)*K + scol;
  const _Float16* Wgp1 = W + (size_t)(n0 + 32 + srow)*K + scol;
  const _Float16* Wgp2 = W + (size_t)(n0 + 64 + srow)*K + scol;
  const _Float16* Wgp3 = W + (size_t)(n0 + 96 + srow)*K + scol;

  auto GSTAGE = [&](int buf, int kk) {
    gload16(Agp0 + kk, &Alds[buf][(      w*64)*8]);
    gload16(Agp1 + kk, &Alds[buf][(256 + w*64)*8]);
    gload16(Wgp0 + kk, &Wlds[buf][(      w*64)*8]);
    gload16(Wgp1 + kk, &Wlds[buf][(256 + w*64)*8]);
    gload16(Wgp2 + kk, &Wlds[buf][(512 + w*64)*8]);
    gload16(Wgp3 + kk, &Wlds[buf][(768 + w*64)*8]);
  };

  const int xr = (fr & 7) << 3;   // read-side XOR (halfs)

  GSTAGE(0, 0);
  int cur = 0;
  for (int kk = 0; kk < K; kk += 64) {
    __syncthreads();                 // buf[cur] staged; prior reads consumed
    if (kk + 64 < K) GSTAGE(cur^1, kk + 64);
#pragma unroll
    for (int ks = 0; ks < 2; ++ks) {
      h8 af[2], wf[4];
#pragma unroll
      for (int mt = 0; mt < 2; ++mt)
        af[mt] = *(const h8*)&Alds[cur][(wm*32 + mt*16 + fr)*64 + ((ks*32 + fq*8) ^ xr)];
#pragma unroll
      for (int nt = 0; nt < 4; ++nt)
        wf[nt] = *(const h8*)&Wlds[cur][(wn*64 + nt*16 + fr)*64 + ((ks*32 + fq*8) ^ xr)];
#pragma unroll
      for (int mt = 0; mt < 2; ++mt)
#pragma unroll
        for (int nt = 0; nt < 4; ++nt)
          acc[mt][nt] = __builtin_amdgcn_mfma_f32_16x16x32_f16(af[mt], wf[nt], acc[mt][nt], 0, 0, 0);
    }
    cur ^= 1;
  }

  // ---- fused epilogue: bias + rope + scatter ----
  const int cb   = (n0 >> 6) + wn;      // 64-col block id, 0..35
  const int matc = cb / 12;             // 0=q, 1=k, 2=v
  const int h    = cb % 12;
  const int mode = (sflags & 1) ? 2 : ((sflags & 2) ? 1 : 0);
  float bv[4];
#pragma unroll
  for (int nt = 0; nt < 4; ++nt) bv[nt] = bias[cb*64 + nt*16 + fr];

  if (matc < 2) {
    const float invf = exp2f((float)fr * -0.4152410118f);  // 100^(-fr/16)
    const float sc = (matc == 0) ? 0.1803368801f : 1.0f;   // q: 0.125*log2e
    _Float16* base = (matc == 0) ? Qd : Kd;
#pragma unroll
    for (int mt = 0; mt < 2; ++mt)
#pragma unroll
      for (int j = 0; j < 4; ++j) {
        const int t = m0 + wm*32 + mt*16 + fq*4 + j;
        const int b = t >> 11, n = t & 2047;
        bool msk;
        if (mode == 1)      msk = mbytes[t] != 0;
        else if (mode == 0) msk = ((const int*)maskraw)[t] != 0;
        else                msk = ((const float*)maskraw)[t] != 0.0f;
        const float py = (float)pos2d[t*2 + 0];
        const float px = (float)pos2d[t*2 + 1];
        float sy, cy, sx, cx;
        __sincosf(py * invf, &sy, &cy);
        __sincosf(px * invf, &sx, &cx);
        const float a0 = acc[mt][0][j] + bv[0], a1 = acc[mt][1][j] + bv[1];
        const float a2 = acc[mt][2][j] + bv[2], a3 = acc[mt][3][j] + bv[3];
        const float r0 = msk ? (a0*cy - a1*sy) : a0;
        const float r1 = msk ? (a1*cy + a0*sy) : a1;
        const float r2 = msk ? (a2*cx - a3*sx) : a2;
        const float r3 = msk ? (a3*cx + a2*sx) : a3;
        _Float16* dst = base + ((size_t)(b*H_ + h)*N_ + n)*64;
        dst[fr]      = (_Float16)(r0 * sc);
        dst[fr + 16] = (_Float16)(r1 * sc);
        dst[fr + 32] = (_Float16)(r2 * sc);
        dst[fr + 48] = (_Float16)(r3 * sc);
      }
  } else {
#pragma unroll
    for (int mt = 0; mt < 2; ++mt)
#pragma unroll
      for (int j = 0; j < 4; ++j) {
        const int t = m0 + wm*32 + mt*16 + fq*4 + j;
        const int b = t >> 11, n = t & 2047;
        _Float16* vb = Vtd + (size_t)(b*H_ + h)*64*N_ + n;
#pragma unroll
        for (int nt = 0; nt < 4; ++nt)
          vb[(size_t)(nt*16 + fr)*N_] = (_Float16)(acc[mt][nt][j] + bv[nt]);
      }
  }
}

// ---------------- GEMM: C[M][N] = A[M][K] * W[N][K]^T + bias (proj) ----------------
// R14/R17-measured-best output path: gload16 staging, dbuf, 1 barrier/iter.
template<int BM, int BN>
__global__ __launch_bounds__(256) void gemm_bt(const _Float16* __restrict__ A,
                                               const _Float16* __restrict__ W,
                                               const float* __restrict__ bias,
                                               _Float16* __restrict__ Ch,
                                               float* __restrict__ Cf,
                                               int M, int N, int K) {
  __shared__ _Float16 Alds[2][BM*32];
  __shared__ _Float16 Wlds[2][BN*32];
  const int tid = threadIdx.x, lane = tid & 63, w = tid >> 6;
  const int flat = blockIdx.y * gridDim.x + blockIdx.x;
  const int wid  = xcd_swz(flat, gridDim.x * gridDim.y);
  const int bx = wid % gridDim.x, by = wid / gridDim.x;
  const int m0 = by*BM, n0 = bx*BN;
  const int wm = w >> 1, wn = w & 1;
  const int fr = lane & 15, fq = lane >> 4;
  constexpr int MT = BM/32, NTt = BN/32;
  constexpr int AI = (BM*4)/256, WI = (BN*4)/256;

  f4 acc[MT][NTt] = {};

  const _Float16* Agp[AI];
  const _Float16* Wgp[WI];
#pragma unroll
  for (int i = 0; i < AI; ++i) { int c = i*256 + tid; Agp[i] = A + (size_t)(m0 + (c>>2))*K + (c&3)*8; }
#pragma unroll
  for (int i = 0; i < WI; ++i) { int c = i*256 + tid; Wgp[i] = W + (size_t)(n0 + (c>>2))*K + (c&3)*8; }

  auto GSTAGE = [&](int buf, int kk) {
#pragma unroll
    for (int i = 0; i < AI; ++i) gload16(Agp[i] + kk, &Alds[buf][(i*256 + w*64)*8]);
#pragma unroll
    for (int i = 0; i < WI; ++i) gload16(Wgp[i] + kk, &Wlds[buf][(i*256 + w*64)*8]);
  };

  GSTAGE(0, 0);
  int cur = 0;
  for (int kk = 0; kk < K; kk += 32) {
    __syncthreads();
    if (kk + 32 < K) GSTAGE(cur^1, kk + 32);
    h8 af[MT], wf[NTt];
#pragma unroll
    for (int mt = 0; mt < MT; ++mt)
      af[mt] = *(const h8*)&Alds[cur][(wm*(BM/2) + mt*16 + fr)*32 + fq*8];
#pragma unroll
    for (int nt = 0; nt < NTt; ++nt)
      wf[nt] = *(const h8*)&Wlds[cur][(wn*(BN/2) + nt*16 + fr)*32 + fq*8];
#pragma unroll
    for (int mt = 0; mt < MT; ++mt)
#pragma unroll
      for (int nt = 0; nt < NTt; ++nt)
        acc[mt][nt] = __builtin_amdgcn_mfma_f32_16x16x32_f16(af[mt], wf[nt], acc[mt][nt], 0, 0, 0);
    cur ^= 1;
  }

#pragma unroll
  for (int nt = 0; nt < NTt; ++nt) {
    const int col = n0 + wn*(BN/2) + nt*16 + fr;
    const float bv = bias[col];
#pragma unroll
    for (int mt = 0; mt < MT; ++mt) {
      const int row = m0 + wm*(BM/2) + mt*16 + fq*4;
#pragma unroll
      for (int j = 0; j < 4; ++j) {
        const float v = acc[mt][nt][j] + bv;
        if (Ch) Ch[(size_t)(row+j)*N + col] = (_Float16)v;
        else    Cf[(size_t)(row+j)*N + col] = v;
      }
    }
  }
}

// ---------------- K4: flash attention (v4.6: launch_bounds 3->5 blocks/CU) ----------------
#define KSPLIT 2
__global__ __launch_bounds__(256, 5) void attn(const _Float16* __restrict__ Q,
                                               const _Float16* __restrict__ K,
                                               const _Float16* __restrict__ Vt,
                                               _Float16* __restrict__ Opart,
                                               float* __restrict__ lpart) {
  __shared__ _Float16 Klds[2][64*64];   // [r][c] holds K[r][c ^ ((r&7)<<3)]
  __shared__ _Float16 Vlds[2][64*64];   // [d][c] holds V^T[d][c ^ ((d&7)<<3)]
  const int tid = threadIdx.x, lane = tid & 63, w = tid >> 6;
  const int q32 = lane & 31;
  const int hi  = lane >> 5;
  const int flat = blockIdx.x + gridDim.x*(blockIdx.y + gridDim.y*blockIdx.z);
  const int wid  = xcd_swz(flat, 16*24*KSPLIT);
  const int qi = wid & 15;
  const int bh = (wid >> 4) % 24;
  const int z  = wid / (16*24);
  const int q0 = qi * 128;
  const int kb0 = z * (N_/KSPLIT), kb1 = kb0 + N_/KSPLIT;
  const _Float16* Qb = Q  + (size_t)bh*N_*64;
  const _Float16* Kb = K  + (size_t)bh*N_*64;
  const _Float16* Vb = Vt + (size_t)bh*64*N_;

  h8 qf[4];
#pragma unroll
  for (int s = 0; s < 4; ++s)
    qf[s] = *(const h8*)&Qb[(size_t)(q0 + w*32 + q32)*64 + s*16 + hi*8];

  f16x o2[2][2];
#pragma unroll
  for (int par = 0; par < 2; ++par)
#pragma unroll
    for (int dg = 0; dg < 2; ++dg)
#pragma unroll
      for (int r = 0; r < 16; ++r) o2[par][dg][r] = 0.f;
  float l_r = 0.f;

  const int sr_l = lane >> 3;
  const int scsw = ((lane & 7) ^ sr_l) * 8;
#define STAGE(buf, kb)                                                          \
  {                                                                             \
    _Float16* kl = &Klds[buf][(w*64)*8];                                        \
    _Float16* vl = &Vlds[buf][(w*64)*8];                                        \
    int r0 = w*8 + sr_l;                                                        \
    gload16(Kb + (size_t)((kb) + r0)*64 + scsw,      kl);                       \
    gload16(Vb + (size_t)r0*N_ + (kb) + scsw,        vl);                       \
    gload16(Kb + (size_t)((kb) + 32 + r0)*64 + scsw, kl + 256*8);               \
    gload16(Vb + (size_t)(32 + r0)*N_ + (kb) + scsw, vl + 256*8);               \
  }

  STAGE(0, kb0);
  int cur = 0;
  const int xr = (q32 & 7) << 3;

  for (int kb = kb0; kb < kb1; kb += 64) {
    __syncthreads();
    if (kb + 64 < kb1) STAGE(cur^1, kb + 64);

#pragma unroll
    for (int kg = 0; kg < 2; ++kg) {
      f16x st;
#pragma unroll
      for (int r = 0; r < 16; ++r) st[r] = -8.65617025f;  // exp-shift in acc init
      __builtin_amdgcn_s_setprio(1);
#pragma unroll
      for (int s = 0; s < 4; ++s) {
        h8 kf = *(const h8*)&Klds[cur][(kg*32 + q32)*64 + ((s*16 + hi*8) ^ xr)];
        st = __builtin_amdgcn_mfma_f32_32x32x16_f16(kf, qf[s], st, 0, 0, 0);
      }
      __builtin_amdgcn_s_setprio(0);
      float p[16];
      float lacc = 0.f;
#pragma unroll
      for (int r = 0; r < 16; ++r) {
        p[r] = __builtin_amdgcn_exp2f(st[r]);   // Q pre-scaled by log2e
        lacc += p[r];
      }
      l_r += lacc;
      uint32_t dd[8];
#pragma unroll
      for (int m = 0; m < 8; ++m)
        dd[m] = __builtin_bit_cast(uint32_t, __builtin_amdgcn_cvt_pkrtz(p[2*m], p[2*m+1]));
#pragma unroll
      for (int s16 = 0; s16 < 2; ++s16) {
        uint32_t e0 = dd[4*s16+0], e2 = dd[4*s16+2];
        asm("v_permlane32_swap_b32 %0, %1" : "+v"(e0), "+v"(e2));
        uint32_t e1 = dd[4*s16+1], e3 = dd[4*s16+3];
        asm("v_permlane32_swap_b32 %0, %1" : "+v"(e1), "+v"(e3));
        u4 bb;
        bb[0] = e0; bb[1] = e1; bb[2] = e2; bb[3] = e3;
        h8 pb = __builtin_bit_cast(h8, bb);
        const int kcol = kg*32 + s16*16 + hi*8;
        __builtin_amdgcn_s_setprio(1);
#pragma unroll
        for (int dg = 0; dg < 2; ++dg) {
          h8 vf = *(const h8*)&Vlds[cur][(dg*32 + q32)*64 + (kcol ^ xr)];
          o2[s16][dg] = __builtin_amdgcn_mfma_f32_32x32x16_f16(vf, pb, o2[s16][dg], 0, 0, 0);
        }
        __builtin_amdgcn_s_setprio(0);
      }
    }
    cur ^= 1;
  }

  l_r += __shfl_xor(l_r, 32);

  _Float16* Ob = Opart + ((size_t)z*24 + bh)*N_*64;
  float*    lb = lpart + ((size_t)z*24 + bh)*N_;
  const int n = q0 + w*32 + q32;
  if (hi == 0) lb[n] = l_r;
#pragma unroll
  for (int dg = 0; dg < 2; ++dg)
#pragma unroll
    for (int rq = 0; rq < 4; ++rq) {
      h4 ov;
#pragma unroll
      for (int j = 0; j < 4; ++j)
        ov[j] = (_Float16)(o2[0][dg][rq*4 + j] + o2[1][dg][rq*4 + j]);
      *(h4*)&Ob[(size_t)n*64 + dg*32 + rq*8 + hi*4] = ov;
    }
}

// ---------------- K5: combine split partials -> AO ----------------
__global__ __launch_bounds__(256) void combine(const _Float16* __restrict__ Opart,
                                               const float* __restrict__ lpart,
                                               _Float16* __restrict__ AO) {
  const int g  = blockIdx.x*256 + threadIdx.x;   // 24*2048*8
  const int d8 = g & 7;
  const int n  = (g >> 3) & 2047;
  const int bh = g >> 14;
  const int b = bh / H_, h = bh % H_;
  const size_t r  = ((size_t)bh*N_ + n);
  const size_t sp = (size_t)24*N_;
  f4 osum[2] = {};
  float l = 0.f;
#pragma unroll
  for (int z = 0; z < KSPLIT; ++z) {
    h8 oz = *(const h8*)&Opart[(r + z*sp)*64 + d8*8];
#pragma unroll
    for (int j = 0; j < 4; ++j) { osum[0][j] += (float)oz[j]; osum[1][j] += (float)oz[j+4]; }
    l += lpart[r + z*sp];
  }
  const float inv = 1.0f / l;
  h8 rr;
#pragma unroll
  for (int j = 0; j < 4; ++j) {
    rr[j]   = (_Float16)(osum[0][j] * inv);
    rr[j+4] = (_Float16)(osum[1][j] * inv);
  }
  *(h8*)&AO[((size_t)b*N_ + n)*C_ + h*64 + d8*8] = rr;
}

// ---------------- launcher ----------------
extern "C" void kernel_launch(void* const* d_in, const int* in_sizes, int n_in,
                              void* d_out, int out_size, void* d_ws, size_t ws_size,
                              hipStream_t stream) {
  (void)in_sizes; (void)n_in; (void)out_size; (void)ws_size;
  const float* x      = (const float*)d_in[0];
  const float* qkv_w  = (const float*)d_in[1];
  const float* qkv_b  = (const float*)d_in[2];
  const float* proj_w = (const float*)d_in[3];
  const float* proj_b = (const float*)d_in[4];
  const int*   pos2d  = (const int*)d_in[5];
  const void*  rmask  = d_in[6];
  float* out = (float*)d_out;
  char* ws = (char*)d_ws;

  // workspace layout (~50 MB of the ~268 MB ws)
  _Float16* Wqh   = (_Float16*)(ws + 0);          // [2304][768]           3.54 MB
  _Float16* Wph   = (_Float16*)(ws + 3538944);    // [768][768]            1.18 MB
  _Float16* Kh    = (_Float16*)(ws + 4718592);    // [24][2048][64]        6.29 MB
  _Float16* Vth   = (_Float16*)(ws + 11010048);   // [24][64][2048]        6.29 MB
  _Float16* Xh    = (_Float16*)(ws + 17301504);   // [4096][768]           6.29 MB
  _Float16* Qh    = (_Float16*)(ws + 23592960);   // [24][2048][64]        6.29 MB
  _Float16* Opart = (_Float16*)(ws + 29884416);   // [2][24][2048][64]    12.58 MB
  float*    lpart = (float*)(ws + 42467328);      // [2][24][2048]         0.39 MB
  _Float16* AOh   = (_Float16*)(ws + 43253760);   // [4096][768]           6.29 MB

  cvt3<<<2688, 256, 0, stream>>>(x, qkv_w, proj_w, Xh, Wqh, Wph);
  gemm_qkv<<<dim3(C3/128, NT/64), 256, 0, stream>>>(Xh, Wqh, qkv_b, pos2d, rmask, Qh, Kh, Vth);
  attn<<<dim3(N_/128, B_*H_, KSPLIT), 256, 0, stream>>>(Qh, Kh, Vth, Opart, lpart);
  combine<<<(24*N_*8)/256, 256, 0, stream>>>(Opart, lpart, AOh);
  gemm_bt<64,64><<<dim3(C_/64, NT/64), 256, 0, stream>>>(AOh, Wph, proj_b, nullptr, out, NT, C_, C_);
}

// Round 21
// 98.730 us; speedup vs baseline: 5.7241x; 5.7241x over previous
//
#include <hip/hip_runtime.h>
#include <stdint.h>

// ---- problem constants ----
#define B_  2
#define N_  2048
#define C_  768
#define H_  12
#define NT  (B_*N_)      // 4096 tokens
#define C3  (3*C_)       // 2304

typedef _Float16 h8 __attribute__((ext_vector_type(8)));   // 4 VGPR, fp16x8 MFMA frag
typedef _Float16 h4 __attribute__((ext_vector_type(4)));
typedef float    f4 __attribute__((ext_vector_type(4)));   // fp32x4 accumulator
typedef float    f16x __attribute__((ext_vector_type(16)));// 32x32 accumulator
typedef uint32_t u4 __attribute__((ext_vector_type(4)));

__device__ __forceinline__ void gload16(const void* g, void* l) {
  // async global->LDS, 16B per lane; LDS dest = wave-uniform base + lane*16
  __builtin_amdgcn_global_load_lds((const __attribute__((address_space(1))) void*)g,
                                   (__attribute__((address_space(3))) void*)l,
                                   16, 0, 0);
}

// T1: XCD-aware bijective block swizzle (m157).  Requires nwg%8==0.
__device__ __forceinline__ int xcd_swz(int flat, int nwg) {
  return (flat & 7) * (nwg >> 3) + (flat >> 3);
}

// ---------------- K1: fp32 -> fp16 convert (x, qkv_w, proj_w) ----------------
__global__ __launch_bounds__(256) void cvt3(const float* __restrict__ x,
                                            const float* __restrict__ w1,
                                            const float* __restrict__ w2,
                                            _Float16* __restrict__ xo,
                                            _Float16* __restrict__ w1o,
                                            _Float16* __restrict__ w2o) {
  const int NX8  = NT*C_/8;     // 393216
  const int NW18 = C3*C_/8;     // 221184
  int c = blockIdx.x*256 + threadIdx.x;
  const float* s; _Float16* d; int off;
  if (c < NX8)            { s = x;  d = xo;  off = c; }
  else if (c < NX8+NW18)  { s = w1; d = w1o; off = c - NX8; }
  else                    { s = w2; d = w2o; off = c - NX8 - NW18; }
  f4 a = *(const f4*)(s + (size_t)off*8);
  f4 b = *(const f4*)(s + (size_t)off*8 + 4);
  h8 o;
#pragma unroll
  for (int j = 0; j < 4; ++j) { o[j] = (_Float16)a[j]; o[j+4] = (_Float16)b[j]; }
  *(h8*)(d + (size_t)off*8) = o;
}

// ---------------- K2: fused QKV GEMM + bias + RoPE2D + scatter ----------------
// v4 (R19): 2D XCD chunking (FETCH 31.6->15.6MB), BK=64, XOR-swizzled LDS
// (conflicts 0), dbuf, 1 barrier/iter.
__global__ __launch_bounds__(256) void gemm_qkv(const _Float16* __restrict__ A,
                                                const _Float16* __restrict__ W,
                                                const float* __restrict__ bias,
                                                const int* __restrict__ pos2d,
                                                const void* __restrict__ maskraw,
                                                _Float16* __restrict__ Qd,
                                                _Float16* __restrict__ Kd,
                                                _Float16* __restrict__ Vtd) {
  constexpr int BM = 64, BN = 128, K = C_;
  __shared__ _Float16 Alds[2][BM*64];   // [row][col^] swizzled, 16 KB
  __shared__ _Float16 Wlds[2][BN*64];   // 32 KB
  __shared__ int sflags;
  const int tid = threadIdx.x, lane = tid & 63, w = tid >> 6;

  // --- sniff rope_mask dtype: 0=int32, 1=uint8/bool, 2=float32 ---
  if (tid == 0) sflags = 0;
  __syncthreads();
  const unsigned char* mbytes = (const unsigned char*)maskraw;
  int fl = 0;
#pragma unroll
  for (int k2 = 0; k2 < 16; ++k2) {
    unsigned char v = mbytes[tid*16 + k2];
    if (v == 0x3f) fl |= 1;
    if ((k2 & 3) && v) fl |= 2;
  }
  if (fl) atomicOr(&sflags, fl);   // visible after any later barrier

  // 2D XCD chunk: wid in [grp*144,(grp+1)*144) -> by = (grp&3)*16 + r/9,
  // bx = (grp>>2)*9 + r%9  (bijective; 3.34MB rectangle per XCD < 4MB L2)
  const int flat = blockIdx.y * gridDim.x + blockIdx.x;
  const int wid  = xcd_swz(flat, 18*64);
  const int grp = wid / 144, rr = wid % 144;
  const int by = (grp & 3)*16 + rr/9;
  const int bx = (grp >> 2)*9 + (rr % 9);
  const int m0 = by*BM, n0 = bx*BN;
  const int wm = w >> 1, wn = w & 1;
  const int fr = lane & 15, fq = lane >> 4;

  f4 acc[2][4] = {};

  // staging: linear LDS dest, pre-swizzled global source col (m173 pattern).
  const int srow = tid >> 3;                      // row-within-32
  const int scol = ((tid & 7) ^ (srow & 7)) * 8;  // swizzled source col (halfs)
  const _Float16* Agp0 = A + (size_t)(m0 +      srow)*K + scol;
  const _Float16* Agp1 = A + (size_t)(m0 + 32 + srow)*K + scol;
  const _Float16* Wgp0 = W + (size_t)(n0 +      srow)*K + scol;
  const _Float16* Wgp1 = W + (size_t)(n0 + 32 + srow)*K + scol;
  const _Float16* Wgp2 = W + (size_t)(n0 + 64 + srow)*K + scol;
  const _Float16* Wgp3 = W + (size_t)(n0 + 96 + srow)*K + scol;

  auto GSTAGE = [&](int buf, int kk) {
    gload16(Agp0 + kk, &Alds[buf][(      w*64)*8]);
    gload16(Agp1 + kk, &Alds[buf][(256 + w*64)*8]);
    gload16(Wgp0 + kk, &Wlds[buf][(      w*64)*8]);
    gload16(Wgp1 + kk, &Wlds[buf][(256 + w*64)*8]);
    gload16(Wgp2 + kk, &Wlds[buf][(512 + w*64)*8]);
    gload16(Wgp3 + kk, &Wlds[buf][(768 + w*64)*8]);
  };

  const int xr = (fr & 7) << 3;   // read-side XOR (halfs)

  GSTAGE(0, 0);
  int cur = 0;
  for (int kk = 0; kk < K; kk += 64) {
    __syncthreads();                 // buf[cur] staged; prior reads consumed
    if (kk + 64 < K) GSTAGE(cur^1, kk + 64);
#pragma unroll
    for (int ks = 0; ks < 2; ++ks) {
      h8 af[2], wf[4];
#pragma unroll
      for (int mt = 0; mt < 2; ++mt)
        af[mt] = *(const h8*)&Alds[cur][(wm*32 + mt*16 + fr)*64 + ((ks*32 + fq*8) ^ xr)];
#pragma unroll
      for (int nt = 0; nt < 4; ++nt)
        wf[nt] = *(const h8*)&Wlds[cur][(wn*64 + nt*16 + fr)*64 + ((ks*32 + fq*8) ^ xr)];
#pragma unroll
      for (int mt = 0; mt < 2; ++mt)
#pragma unroll
        for (int nt = 0; nt < 4; ++nt)
          acc[mt][nt] = __builtin_amdgcn_mfma_f32_16x16x32_f16(af[mt], wf[nt], acc[mt][nt], 0, 0, 0);
    }
    cur ^= 1;
  }

  // ---- fused epilogue: bias + rope + scatter ----
  const int cb   = (n0 >> 6) + wn;      // 64-col block id, 0..35
  const int matc = cb / 12;             // 0=q, 1=k, 2=v
  const int h    = cb % 12;
  const int mode = (sflags & 1) ? 2 : ((sflags & 2) ? 1 : 0);
  float bv[4];
#pragma unroll
  for (int nt = 0; nt < 4; ++nt) bv[nt] = bias[cb*64 + nt*16 + fr];

  if (matc < 2) {
    const float invf = exp2f((float)fr * -0.4152410118f);  // 100^(-fr/16)
    const float sc = (matc == 0) ? 0.1803368801f : 1.0f;   // q: 0.125*log2e
    _Float16* base = (matc == 0) ? Qd : Kd;
#pragma unroll
    for (int mt = 0; mt < 2; ++mt)
#pragma unroll
      for (int j = 0; j < 4; ++j) {
        const int t = m0 + wm*32 + mt*16 + fq*4 + j;
        const int b = t >> 11, n = t & 2047;
        bool msk;
        if (mode == 1)      msk = mbytes[t] != 0;
        else if (mode == 0) msk = ((const int*)maskraw)[t] != 0;
        else                msk = ((const float*)maskraw)[t] != 0.0f;
        const float py = (float)pos2d[t*2 + 0];
        const float px = (float)pos2d[t*2 + 1];
        float sy, cy, sx, cx;
        __sincosf(py * invf, &sy, &cy);
        __sincosf(px * invf, &sx, &cx);
        const float a0 = acc[mt][0][j] + bv[0], a1 = acc[mt][1][j] + bv[1];
        const float a2 = acc[mt][2][j] + bv[2], a3 = acc[mt][3][j] + bv[3];
        const float r0 = msk ? (a0*cy - a1*sy) : a0;
        const float r1 = msk ? (a1*cy + a0*sy) : a1;
        const float r2 = msk ? (a2*cx - a3*sx) : a2;
        const float r3 = msk ? (a3*cx + a2*sx) : a3;
        _Float16* dst = base + ((size_t)(b*H_ + h)*N_ + n)*64;
        dst[fr]      = (_Float16)(r0 * sc);
        dst[fr + 16] = (_Float16)(r1 * sc);
        dst[fr + 32] = (_Float16)(r2 * sc);
        dst[fr + 48] = (_Float16)(r3 * sc);
      }
  } else {
#pragma unroll
    for (int mt = 0; mt < 2; ++mt)
#pragma unroll
      for (int j = 0; j < 4; ++j) {
        const int t = m0 + wm*32 + mt*16 + fq*4 + j;
        const int b = t >> 11, n = t & 2047;
        _Float16* vb = Vtd + (size_t)(b*H_ + h)*64*N_ + n;
#pragma unroll
        for (int nt = 0; nt < 4; ++nt)
          vb[(size_t)(nt*16 + fr)*N_] = (_Float16)(acc[mt][nt][j] + bv[nt]);
      }
  }
}

// ---------------- GEMM: C[M][N] = A[M][K] * W[N][K]^T + bias (proj) ----------------
template<int BM, int BN>
__global__ __launch_bounds__(256) void gemm_bt(const _Float16* __restrict__ A,
                                               const _Float16* __restrict__ W,
                                               const float* __restrict__ bias,
                                               _Float16* __restrict__ Ch,
                                               float* __restrict__ Cf,
                                               int M, int N, int K) {
  __shared__ _Float16 Alds[2][BM*32];
  __shared__ _Float16 Wlds[2][BN*32];
  const int tid = threadIdx.x, lane = tid & 63, w = tid >> 6;
  const int flat = blockIdx.y * gridDim.x + blockIdx.x;
  const int wid  = xcd_swz(flat, gridDim.x * gridDim.y);
  const int bx = wid % gridDim.x, by = wid / gridDim.x;
  const int m0 = by*BM, n0 = bx*BN;
  const int wm = w >> 1, wn = w & 1;
  const int fr = lane & 15, fq = lane >> 4;
  constexpr int MT = BM/32, NTt = BN/32;
  constexpr int AI = (BM*4)/256, WI = (BN*4)/256;

  f4 acc[MT][NTt] = {};

  const _Float16* Agp[AI];
  const _Float16* Wgp[WI];
#pragma unroll
  for (int i = 0; i < AI; ++i) { int c = i*256 + tid; Agp[i] = A + (size_t)(m0 + (c>>2))*K + (c&3)*8; }
#pragma unroll
  for (int i = 0; i < WI; ++i) { int c = i*256 + tid; Wgp[i] = W + (size_t)(n0 + (c>>2))*K + (c&3)*8; }

  auto GSTAGE = [&](int buf, int kk) {
#pragma unroll
    for (int i = 0; i < AI; ++i) gload16(Agp[i] + kk, &Alds[buf][(i*256 + w*64)*8]);
#pragma unroll
    for (int i = 0; i < WI; ++i) gload16(Wgp[i] + kk, &Wlds[buf][(i*256 + w*64)*8]);
  };

  GSTAGE(0, 0);
  int cur = 0;
  for (int kk = 0; kk < K; kk += 32) {
    __syncthreads();
    if (kk + 32 < K) GSTAGE(cur^1, kk + 32);
    h8 af[MT], wf[NTt];
#pragma unroll
    for (int mt = 0; mt < MT; ++mt)
      af[mt] = *(const h8*)&Alds[cur][(wm*(BM/2) + mt*16 + fr)*32 + fq*8];
#pragma unroll
    for (int nt = 0; nt < NTt; ++nt)
      wf[nt] = *(const h8*)&Wlds[cur][(wn*(BN/2) + nt*16 + fr)*32 + fq*8];
#pragma unroll
    for (int mt = 0; mt < MT; ++mt)
#pragma unroll
      for (int nt = 0; nt < NTt; ++nt)
        acc[mt][nt] = __builtin_amdgcn_mfma_f32_16x16x32_f16(af[mt], wf[nt], acc[mt][nt], 0, 0, 0);
    cur ^= 1;
  }

#pragma unroll
  for (int nt = 0; nt < NTt; ++nt) {
    const int col = n0 + wn*(BN/2) + nt*16 + fr;
    const float bv = bias[col];
#pragma unroll
    for (int mt = 0; mt < MT; ++mt) {
      const int row = m0 + wm*(BM/2) + mt*16 + fq*4;
#pragma unroll
      for (int j = 0; j < 4; ++j) {
        const float v = acc[mt][nt][j] + bv;
        if (Ch) Ch[(size_t)(row+j)*N + col] = (_Float16)v;
        else    Cf[(size_t)(row+j)*N + col] = v;
      }
    }
  }
}

// ---------------- K4: flash attention (v4.4, launch_bounds REVERTED to 3) ----------------
// R20 lesson: (256,5) forced VGPR 68->48 -> o2/qf spilled to scratch ->
// FETCH 939MB, 508us.  The bound constrains the allocator; 3 blocks/CU is
// the no-spill optimum for this kernel.
#define KSPLIT 2
__global__ __launch_bounds__(256, 3) void attn(const _Float16* __restrict__ Q,
                                               const _Float16* __restrict__ K,
                                               const _Float16* __restrict__ Vt,
                                               _Float16* __restrict__ Opart,
                                               float* __restrict__ lpart) {
  __shared__ _Float16 Klds[2][64*64];   // [r][c] holds K[r][c ^ ((r&7)<<3)]
  __shared__ _Float16 Vlds[2][64*64];   // [d][c] holds V^T[d][c ^ ((d&7)<<3)]
  const int tid = threadIdx.x, lane = tid & 63, w = tid >> 6;
  const int q32 = lane & 31;
  const int hi  = lane >> 5;
  const int flat = blockIdx.x + gridDim.x*(blockIdx.y + gridDim.y*blockIdx.z);
  const int wid  = xcd_swz(flat, 16*24*KSPLIT);
  const int qi = wid & 15;
  const int bh = (wid >> 4) % 24;
  const int z  = wid / (16*24);
  const int q0 = qi * 128;
  const int kb0 = z * (N_/KSPLIT), kb1 = kb0 + N_/KSPLIT;
  const _Float16* Qb = Q  + (size_t)bh*N_*64;
  const _Float16* Kb = K  + (size_t)bh*N_*64;
  const _Float16* Vb = Vt + (size_t)bh*64*N_;

  h8 qf[4];
#pragma unroll
  for (int s = 0; s < 4; ++s)
    qf[s] = *(const h8*)&Qb[(size_t)(q0 + w*32 + q32)*64 + s*16 + hi*8];

  f16x o2[2][2];
#pragma unroll
  for (int par = 0; par < 2; ++par)
#pragma unroll
    for (int dg = 0; dg < 2; ++dg)
#pragma unroll
      for (int r = 0; r < 16; ++r) o2[par][dg][r] = 0.f;
  float l_r = 0.f;

  const int sr_l = lane >> 3;
  const int scsw = ((lane & 7) ^ sr_l) * 8;
#define STAGE(buf, kb)                                                          \
  {                                                                             \
    _Float16* kl = &Klds[buf][(w*64)*8];                                        \
    _Float16* vl = &Vlds[buf][(w*64)*8];                                        \
    int r0 = w*8 + sr_l;                                                        \
    gload16(Kb + (size_t)((kb) + r0)*64 + scsw,      kl);                       \
    gload16(Vb + (size_t)r0*N_ + (kb) + scsw,        vl);                       \
    gload16(Kb + (size_t)((kb) + 32 + r0)*64 + scsw, kl + 256*8);               \
    gload16(Vb + (size_t)(32 + r0)*N_ + (kb) + scsw, vl + 256*8);               \
  }

  STAGE(0, kb0);
  int cur = 0;
  const int xr = (q32 & 7) << 3;

  for (int kb = kb0; kb < kb1; kb += 64) {
    __syncthreads();
    if (kb + 64 < kb1) STAGE(cur^1, kb + 64);

#pragma unroll
    for (int kg = 0; kg < 2; ++kg) {
      f16x st;
#pragma unroll
      for (int r = 0; r < 16; ++r) st[r] = -8.65617025f;  // exp-shift in acc init
      __builtin_amdgcn_s_setprio(1);
#pragma unroll
      for (int s = 0; s < 4; ++s) {
        h8 kf = *(const h8*)&Klds[cur][(kg*32 + q32)*64 + ((s*16 + hi*8) ^ xr)];
        st = __builtin_amdgcn_mfma_f32_32x32x16_f16(kf, qf[s], st, 0, 0, 0);
      }
      __builtin_amdgcn_s_setprio(0);
      float p[16];
      float lacc = 0.f;
#pragma unroll
      for (int r = 0; r < 16; ++r) {
        p[r] = __builtin_amdgcn_exp2f(st[r]);   // Q pre-scaled by log2e
        lacc += p[r];
      }
      l_r += lacc;
      uint32_t dd[8];
#pragma unroll
      for (int m = 0; m < 8; ++m)
        dd[m] = __builtin_bit_cast(uint32_t, __builtin_amdgcn_cvt_pkrtz(p[2*m], p[2*m+1]));
#pragma unroll
      for (int s16 = 0; s16 < 2; ++s16) {
        uint32_t e0 = dd[4*s16+0], e2 = dd[4*s16+2];
        asm("v_permlane32_swap_b32 %0, %1" : "+v"(e0), "+v"(e2));
        uint32_t e1 = dd[4*s16+1], e3 = dd[4*s16+3];
        asm("v_permlane32_swap_b32 %0, %1" : "+v"(e1), "+v"(e3));
        u4 bb;
        bb[0] = e0; bb[1] = e1; bb[2] = e2; bb[3] = e3;
        h8 pb = __builtin_bit_cast(h8, bb);
        const int kcol = kg*32 + s16*16 + hi*8;
        __builtin_amdgcn_s_setprio(1);
#pragma unroll
        for (int dg = 0; dg < 2; ++dg) {
          h8 vf = *(const h8*)&Vlds[cur][(dg*32 + q32)*64 + (kcol ^ xr)];
          o2[s16][dg] = __builtin_amdgcn_mfma_f32_32x32x16_f16(vf, pb, o2[s16][dg], 0, 0, 0);
        }
        __builtin_amdgcn_s_setprio(0);
      }
    }
    cur ^= 1;
  }

  l_r += __shfl_xor(l_r, 32);

  _Float16* Ob = Opart + ((size_t)z*24 + bh)*N_*64;
  float*    lb = lpart + ((size_t)z*24 + bh)*N_;
  const int n = q0 + w*32 + q32;
  if (hi == 0) lb[n] = l_r;
#pragma unroll
  for (int dg = 0; dg < 2; ++dg)
#pragma unroll
    for (int rq = 0; rq < 4; ++rq) {
      h4 ov;
#pragma unroll
      for (int j = 0; j < 4; ++j)
        ov[j] = (_Float16)(o2[0][dg][rq*4 + j] + o2[1][dg][rq*4 + j]);
      *(h4*)&Ob[(size_t)n*64 + dg*32 + rq*8 + hi*4] = ov;
    }
}

// ---------------- K5: combine split partials -> AO ----------------
__global__ __launch_bounds__(256) void combine(const _Float16* __restrict__ Opart,
                                               const float* __restrict__ lpart,
                                               _Float16* __restrict__ AO) {
  const int g  = blockIdx.x*256 + threadIdx.x;   // 24*2048*8
  const int d8 = g & 7;
  const int n  = (g >> 3) & 2047;
  const int bh = g >> 14;
  const int b = bh / H_, h = bh % H_;
  const size_t r  = ((size_t)bh*N_ + n);
  const size_t sp = (size_t)24*N_;
  f4 osum[2] = {};
  float l = 0.f;
#pragma unroll
  for (int z = 0; z < KSPLIT; ++z) {
    h8 oz = *(const h8*)&Opart[(r + z*sp)*64 + d8*8];
#pragma unroll
    for (int j = 0; j < 4; ++j) { osum[0][j] += (float)oz[j]; osum[1][j] += (float)oz[j+4]; }
    l += lpart[r + z*sp];
  }
  const float inv = 1.0f / l;
  h8 rr;
#pragma unroll
  for (int j = 0; j < 4; ++j) {
    rr[j]   = (_Float16)(osum[0][j] * inv);
    rr[j+4] = (_Float16)(osum[1][j] * inv);
  }
  *(h8*)&AO[((size_t)b*N_ + n)*C_ + h*64 + d8*8] = rr;
}

// ---------------- launcher ----------------
extern "C" void kernel_launch(void* const* d_in, const int* in_sizes, int n_in,
                              void* d_out, int out_size, void* d_ws, size_t ws_size,
                              hipStream_t stream) {
  (void)in_sizes; (void)n_in; (void)out_size; (void)ws_size;
  const float* x      = (const float*)d_in[0];
  const float* qkv_w  = (const float*)d_in[1];
  const float* qkv_b  = (const float*)d_in[2];
  const float* proj_w = (const float*)d_in[3];
  const float* proj_b = (const float*)d_in[4];
  const int*   pos2d  = (const int*)d_in[5];
  const void*  rmask  = d_in[6];
  float* out = (float*)d_out;
  char* ws = (char*)d_ws;

  // workspace layout (~50 MB of the ~268 MB ws)
  _Float16* Wqh   = (_Float16*)(ws + 0);          // [2304][768]           3.54 MB
  _Float16* Wph   = (_Float16*)(ws + 3538944);    // [768][768]            1.18 MB
  _Float16* Kh    = (_Float16*)(ws + 4718592);    // [24][2048][64]        6.29 MB
  _Float16* Vth   = (_Float16*)(ws + 11010048);   // [24][64][2048]        6.29 MB
  _Float16* Xh    = (_Float16*)(ws + 17301504);   // [4096][768]           6.29 MB
  _Float16* Qh    = (_Float16*)(ws + 23592960);   // [24][2048][64]        6.29 MB
  _Float16* Opart = (_Float16*)(ws + 29884416);   // [2][24][2048][64]    12.58 MB
  float*    lpart = (float*)(ws + 42467328);      // [2][24][2048]         0.39 MB
  _Float16* AOh   = (_Float16*)(ws + 43253760);   // [4096][768]           6.29 MB

  cvt3<<<2688, 256, 0, stream>>>(x, qkv_w, proj_w, Xh, Wqh, Wph);
  gemm_qkv<<<dim3(C3/128, NT/64), 256, 0, stream>>>(Xh, Wqh, qkv_b, pos2d, rmask, Qh, Kh, Vth);
  attn<<<dim3(N_/128, B_*H_, KSPLIT), 256, 0, stream>>>(Qh, Kh, Vth, Opart, lpart);
  combine<<<(24*N_*8)/256, 256, 0, stream>>>(Opart, lpart, AOh);
  gemm_bt<64,64><<<dim3(C_/64, NT/64), 256, 0, stream>>>(AOh, Wph, proj_b, nullptr, out, NT, C_, C_);
}